// Round 4
// baseline (1253.088 us; speedup 1.0000x reference)
//
#include <hip/hip_runtime.h>
#include <math.h>
#include <type_traits>

// TVB MPR simulation + BOLD, v4: time-paired b64 gather, dual-copy ring.
//
// 768 threads = 12 waves:
//   waves 0-7 : coupling gather, 4 threads/region, 32 term-slots each.
//               Old terms (lag>=3): ds_read_b64 fetches (r(t), r(t+1)) ->
//               one read per TWO steps. Slot k<16 reads at even s, k>=16 at
//               odd s (dual-copy ring makes alignment a free choice).
//   waves 8-9 : MPR Heun update (1 thread/region).
//   waves 10-11: BOLD Heun chain, one step behind.
//
// Ring (128 KB): 64 pair-units x 2048 B. Unit P: bytes [0,1024) = copyA pair
// (times 2P, 2P+1), [1024,2048) = copyB pair (times 2P+1, 2P+2), each row
// float2 per region j at j*8. Time X: copyA at ((X>>1)&63)*2048+(X&1)*4+j*8;
// copyB at (((X-1)>>1)&63)*2048+1024+((X&1)^1)*4+j*8.
// Fresh terms (lag<=2) read per-step from a 4-slot ring rsmall[4][128].
//
// Phase A (per step): fresh adds -> cbuf; noise prefetch; BOLD r-read.
// Phase B: old-gather for time s+2 (bulk) || MPR(s) || BOLD(s-1).

namespace {
constexpr int NREG  = 128;
constexpr int NSTEP = 1000;

__device__ __forceinline__ float fsqrt_raw(float x){ float r; asm("v_sqrt_f32 %0, %1" : "=v"(r) : "v"(x)); return r; }
__device__ __forceinline__ float frcp_raw (float x){ float r; asm("v_rcp_f32 %0, %1" : "=v"(r) : "v"(x)); return r; }
__device__ __forceinline__ float fexp2_raw(float x){ float r; asm("v_exp_f32 %0, %1" : "=v"(r) : "v"(x)); return r; }

__device__ __forceinline__ float pow3125(float v) {
    float s1 = fsqrt_raw(v);
    float s2 = fsqrt_raw(s1);
    float s3 = fsqrt_raw(s2);
    return v * v * v * s3;
}

__device__ __forceinline__ float dpp_add_xor1(float x){
    int y = __builtin_amdgcn_mov_dpp(__float_as_int(x), 0xB1, 0xF, 0xF, true); // [1,0,3,2]
    return x + __int_as_float(y);
}
__device__ __forceinline__ float dpp_add_xor2(float x){
    int y = __builtin_amdgcn_mov_dpp(__float_as_int(x), 0x4E, 0xF, 0xF, true); // [2,3,0,1]
    return x + __int_as_float(y);
}
} // namespace

__launch_bounds__(768, 1)
__global__ void tvb_kernel(const float* __restrict__ region_pars,  // (128,1)
                           const float* __restrict__ Wt,           // (128,128,1)
                           const float* __restrict__ g,            // (1,)
                           const float* __restrict__ stimulus,     // (100,1)
                           const float* __restrict__ noise,        // (100,10,128,2)
                           const float* __restrict__ initial_cond, // (128,2)
                           const int*   __restrict__ lags,         // (128,128)
                           float* __restrict__ out)                // rv(1000,128,2) ++ bold(128)
{
    __shared__ float hist[32768];        // 128 KB dual-copy pair ring
    __shared__ float cbuf[NREG];         // per-step coupling sums
    __shared__ float rsmall[4 * NREG];   // recent-r ring (fresh terms + BOLD)

    const int tid = (int)threadIdx.x;
    const int wid = tid >> 6;
    char* histc = (char*)hist;
    char* rsmc  = (char*)rsmall;

    // ---- constants ----
    constexpr float ONE_PI = (float)(1.0 / 3.14159265358979323846);
    constexpr float PI_F   = (float)3.14159265358979323846;
    constexpr float RTS    = (float)(1.0 / 0.65);
    constexpr float RTF    = (float)(1.0 / 0.41);
    constexpr float RTO    = (float)(1.0 / 0.98);
    constexpr float K1     = (float)(4.3 * 40.3 * 0.4 * 0.04);
    constexpr float K2     = (float)(0.5 * 25.0 * 0.4 * 0.04);
    constexpr float L06    = -0.7369655941662062f;                  // log2(0.6)
    const float DWS = 0.01f * sqrtf(0.1f);

    // ---- init: r0 -> cbuf, then fill rings ----
    if (tid < NREG) cbuf[tid] = initial_cond[2 * tid];
    __syncthreads();
    for (int e = tid; e < 16384; e += 768) {       // float2 unit e: region e&127
        const float v = cbuf[e & 127];
        *reinterpret_cast<float2*>(histc + (size_t)e * 8) = make_float2(v, v);
    }
    if (tid < 512) rsmall[tid] = cbuf[tid & 127];
    __syncthreads();

    // ================= per-role persistent state =================
    float wreg[32]; int A[32]; float pend[32];
    float aOld = 0.f;
    int   nF = 0;
    float wF0=0,wF1=0,wF2=0,wF3=0,wF4=0,wF5=0,wF6=0,wF7=0;
    int   LJ0=0,LJ1=0,LJ2=0,LJ3=0,LJ4=0,LJ5=0,LJ6=0,LJ7=0; // (lag<<20)|(j<<2)

    float xr=0.f, xV=0.f, eta=0.f, g0=0.f, c_cur=0.f;
    float2 nz = make_float2(0.f,0.f), nz_next = make_float2(0.f,0.f);
    float stim_i = 0.f, xb = 0.f;
    const int i2 = tid - 512;   // region for MPR waves
    const int i3 = tid - 640;   // region for BOLD waves
    float bs=1.f, bf=1.f, bv=1.f, bq=1.f;

    if (wid < 8) {
        const int i    = tid >> 2;
        const int h    = tid & 3;
        const int lane = tid & 63;
        const int rot  = (lane >> 2) + ((lane & 3) << 3);
#pragma unroll
        for (int k = 0; k < 32; ++k) {
            const int j  = (h << 5) | ((k + rot) & 31);
            const float ww = Wt[i * NREG + j];
            const int lg = lags[i * NREG + j];
            const int ph = (k < 16) ? 0 : 1;          // read-step parity
            const int t  = ph + 2 - lg + 256;         // biased first t_need
            const int A0 = (((t >> 1) & 63) << 11) | ((t & 1) << 10) | (j << 3);
            A[k] = (A0 + (131072 - 2048)) & 0x1FFFF;  // pre-decremented
            pend[k] = 0.f;
            if (lg <= 2) {
                wreg[k] = 0.f;
                const int lj = (lg << 20) | (j << 2);
                if      (nF == 0) { wF0 = ww; LJ0 = lj; }
                else if (nF == 1) { wF1 = ww; LJ1 = lj; }
                else if (nF == 2) { wF2 = ww; LJ2 = lj; }
                else if (nF == 3) { wF3 = ww; LJ3 = lj; }
                else if (nF == 4) { wF4 = ww; LJ4 = lj; }
                else if (nF == 5) { wF5 = ww; LJ5 = lj; }
                else if (nF == 6) { wF6 = ww; LJ6 = lj; }
                else              { wF7 = ww; LJ7 = lj; }
                ++nF;
            } else {
                wreg[k] = ww;
            }
        }
        // prologue: old-part(T=1) and full c(0); all history = r0
        float sOld = 0.f;
#pragma unroll
        for (int k = 0; k < 32; ++k)
            sOld = fmaf(wreg[k], *(const float*)(histc + (A[k] & 0x3F8)), sOld);
        float cful = sOld;
#define FRESH_PRO(c, WF, LJ) if (nF > c) cful = fmaf(WF, *(const float*)(histc + ((LJ & 0x3FC) << 1)), cful);
        FRESH_PRO(0, wF0, LJ0) FRESH_PRO(1, wF1, LJ1) FRESH_PRO(2, wF2, LJ2) FRESH_PRO(3, wF3, LJ3)
        FRESH_PRO(4, wF4, LJ4) FRESH_PRO(5, wF5, LJ5) FRESH_PRO(6, wF6, LJ6) FRESH_PRO(7, wF7, LJ7)
#undef FRESH_PRO
        aOld = sOld;
#pragma unroll
        for (int k = 16; k < 32; ++k)     // preload odd-phase pend (times <= -1 -> r0)
            pend[k] = *(const float*)(histc + (A[k] & 0x3F8));
        cful = dpp_add_xor1(cful);
        cful = dpp_add_xor2(cful);
        if ((tid & 3) == 0) cbuf[tid >> 2] = cful;   // c(0)
    }
    __syncthreads();
    if (wid == 8 || wid == 9) {
        c_cur = cbuf[i2];
        eta   = region_pars[i2];
        g0    = g[0];
        xr    = initial_cond[2 * i2];
        xV    = initial_cond[2 * i2 + 1];
        nz    = *reinterpret_cast<const float2*>(&noise[(size_t)i2 * 2]);
    }
    __syncthreads();

    auto bstep = [&](float x) {
        const float pv1 = pow3125(bv);
        const float e1  = fexp2_raw(L06 * frcp_raw(bf));
        const float d1s = x - RTS * bs - RTF * (bf - 1.f);
        const float d1f = bs;
        const float d1v = RTO * (bf - pv1);
        const float d1q = RTO * (bf * (1.f - e1) * 2.5f - pv1 * bq * frcp_raw(bv));
        const float s2v = bs + 0.01f * d1s;
        const float f2v = bf + 0.01f * d1f;
        const float v2v = bv + 0.01f * d1v;
        const float q2v = bq + 0.01f * d1q;
        const float pv2 = pow3125(v2v);
        const float e2  = fexp2_raw(L06 * frcp_raw(f2v));
        const float d2s = x - RTS * s2v - RTF * (f2v - 1.f);
        const float d2f = s2v;
        const float d2v = RTO * (f2v - pv2);
        const float d2q = RTO * (f2v * (1.f - e2) * 2.5f - pv2 * q2v * frcp_raw(v2v));
        bs += 0.005f * (d1s + d2s);
        bf += 0.005f * (d1f + d2f);
        bv += 0.005f * (d1v + d2v);
        bq += 0.005f * (d1q + d2q);
    };

    auto stepBody = [&](auto PHC, int s) {
        constexpr int PH = decltype(PHC)::value;   // == s & 1
        // ---------- phase A ----------
        if (wid < 8) {
            float a = aOld;                         // old part for time s+1
            const int S1 = s + 1;
#define FRESH_ADD(c, WF, LJ) if (nF > c) { const int X = S1 - (LJ >> 20); \
            a = fmaf(WF, *(const float*)(rsmc + (((X & 3) << 9) | (LJ & 0x3FC))), a); }
            FRESH_ADD(0, wF0, LJ0) FRESH_ADD(1, wF1, LJ1) FRESH_ADD(2, wF2, LJ2) FRESH_ADD(3, wF3, LJ3)
            FRESH_ADD(4, wF4, LJ4) FRESH_ADD(5, wF5, LJ5) FRESH_ADD(6, wF6, LJ6) FRESH_ADD(7, wF7, LJ7)
#undef FRESH_ADD
            a = dpp_add_xor1(a);
            a = dpp_add_xor2(a);
            if ((tid & 3) == 0) cbuf[tid >> 2] = a; // c(s+1)
        } else if (wid < 10) {
            const int sn = (s < NSTEP - 1) ? s + 1 : NSTEP - 1;
            nz_next = *reinterpret_cast<const float2*>(&noise[(size_t)(sn * NREG + i2) * 2]);
            stim_i  = (i2 == 0) ? stimulus[s / 10] : 0.f;
        } else {
            xb = rsmall[((s & 3) << 7) + i3];       // r(s)
        }
        __syncthreads();
        // ---------- phase B ----------
        if (wid < 8) {
            float acc = 0.f;                        // old part for time s+2
#pragma unroll
            for (int k = 0; k < 32; ++k) {
                if ((k < 16) == (PH == 0)) {        // reader this step
                    A[k] = (A[k] + 2048) & 0x1FFFF;
                    const float2 v = *reinterpret_cast<const float2*>(histc + A[k]);
                    acc = fmaf(wreg[k], v.x, acc);
                    pend[k] = v.y;
                } else {
                    acc = fmaf(wreg[k], pend[k], acc);
                }
            }
            aOld = acc;
        } else if (wid < 10) {
            const float c_next = cbuf[i2];
            const float dw_r = DWS * nz.x;
            const float dw_V = DWS * nz.y;

            const float I1  = g0 * c_cur + stim_i;
            const float dr1 = ONE_PI + (2.0f * xr) * xV;
            const float p1  = PI_F * xr;
            const float dV1 = ((xV * xV + eta) + 15.0f * xr + I1) - p1 * p1;

            const float xir = fmaxf((xr + 0.1f * dr1) + dw_r, 0.f);
            const float xiV = (xV + 0.1f * dV1) + dw_V;

            const float I2  = g0 * c_next + stim_i;
            const float dr2 = ONE_PI + (2.0f * xir) * xiV;
            const float p2  = PI_F * xir;
            const float dV2 = ((xiV * xiV + eta) + 15.0f * xir + I2) - p2 * p2;

            const float nxr = fmaxf((xr + 0.05f * (dr1 + dr2)) + dw_r, 0.f);
            const float nxV = (xV + 0.05f * (dV1 + dV2)) + dw_V;

            const int X = s + 1;
            rsmall[((X & 3) << 7) + i2] = nxr;
            // copyA: pair (X>>1)&63, dword X&1
            *(float*)(histc + ((((X >> 1) & 63) << 11) | ((X & 1) << 2) | (i2 << 3))) = nxr;
            // copyB: pair ((X-1)>>1)&63, +1024, dword (X&1)^1
            *(float*)(histc + (((((X - 1) >> 1) & 63) << 11) | 1024 | (((X & 1) ^ 1) << 2) | (i2 << 3))) = nxr;
            *reinterpret_cast<float2*>(&out[(size_t)(s * NREG + i2) * 2]) =
                make_float2(nxr, nxV);

            c_cur = c_next;
            xr = nxr;
            xV = nxV;
            nz = nz_next;
        } else {
            if (s > 0) bstep(xb);
        }
        __syncthreads();
    };

    for (int sp = 0; sp < NSTEP / 2; ++sp) {
        stepBody(std::integral_constant<int,0>{}, 2 * sp);
        stepBody(std::integral_constant<int,1>{}, 2 * sp + 1);
    }

    // ---- epilogue: last BOLD input r(1000), then bold output ----
    if (wid >= 10) {
        const float x = rsmall[((NSTEP & 3) << 7) + i3];
        bstep(x);
        const float bold = 4.0f * (K1 * (1.f - bq) + K2 * (1.f - bq * frcp_raw(bv))
                                   + 0.5f * (1.f - bv));
        out[(size_t)NSTEP * NREG * 2 + i3] = bold;
    }
}

extern "C" void kernel_launch(void* const* d_in, const int* in_sizes, int n_in,
                              void* d_out, int out_size, void* d_ws, size_t ws_size,
                              hipStream_t stream) {
    const float* region_pars  = (const float*)d_in[0];
    const float* Wt           = (const float*)d_in[1];
    const float* g            = (const float*)d_in[2];
    const float* stimulus     = (const float*)d_in[3];
    const float* noise        = (const float*)d_in[4];
    const float* initial_cond = (const float*)d_in[5];
    const int*   lags         = (const int*)d_in[6];
    // d_in[7] = ix_lag_from: always tile(arange(N)) -> implicit in our layout

    tvb_kernel<<<dim3(1), dim3(768), 0, stream>>>(
        region_pars, Wt, g, stimulus, noise, initial_cond, lags, (float*)d_out);
}

// Round 5
// 1148.323 us; speedup vs baseline: 1.0912x; 1.0912x over previous
//
#include <hip/hip_runtime.h>
#include <math.h>
#include <type_traits>

// TVB MPR simulation + BOLD, v5: ds_read2 time-pairing + raw barriers.
//
// 768 threads = 12 waves:
//   waves 0-7 : coupling gather, 4 threads/region, 32 term-slots each.
//               Old terms (lag>=3): one ds_read2_b32 fetches r(t) AND r(t+1)
//               (ring slots 512B apart) -> one DS instr per TWO steps.
//               k<16 reads at even s, k>=16 at odd s; two rolling partials
//               P0 (coupling at s+2) / P1 (s+3) replace any stash array.
//   waves 8-9 : MPR Heun update (1 thread/region).
//   waves 10-11: BOLD Heun chain, one step behind.
//
// Barriers are RAW (s_waitcnt lgkmcnt(0) + s_barrier): no vmcnt(0) drain, so
// noise-load / rv-store latency is never exposed at the per-step barriers
// (v4's regression cause).
//
// Ring: lds[slot*128 + j], slot = time & 255, PLUS duplicate row slot 256
// (mirror of slot 0) so the pair read at slot 255 lands in-bounds.
// Fresh terms (lag<=2) are added per-step in phase A from the ring directly.

namespace {
constexpr int NREG  = 128;
constexpr int NSTEP = 1000;
constexpr int HISTF = 257 * NREG;          // floats in ring (incl. dup row)

__device__ __forceinline__ float fsqrt_raw(float x){ float r; asm("v_sqrt_f32 %0, %1" : "=v"(r) : "v"(x)); return r; }
__device__ __forceinline__ float frcp_raw (float x){ float r; asm("v_rcp_f32 %0, %1" : "=v"(r) : "v"(x)); return r; }
__device__ __forceinline__ float fexp2_raw(float x){ float r; asm("v_exp_f32 %0, %1" : "=v"(r) : "v"(x)); return r; }

__device__ __forceinline__ float pow3125(float v) {
    float s1 = fsqrt_raw(v);
    float s2 = fsqrt_raw(s1);
    float s3 = fsqrt_raw(s2);
    return v * v * v * s3;
}

__device__ __forceinline__ float dpp_add_xor1(float x){
    int y = __builtin_amdgcn_mov_dpp(__float_as_int(x), 0xB1, 0xF, 0xF, true); // [1,0,3,2]
    return x + __int_as_float(y);
}
__device__ __forceinline__ float dpp_add_xor2(float x){
    int y = __builtin_amdgcn_mov_dpp(__float_as_int(x), 0x4E, 0xF, 0xF, true); // [2,3,0,1]
    return x + __int_as_float(y);
}

// raw workgroup barrier: LDS drained, global ops keep flying (no vmcnt(0))
__device__ __forceinline__ void wg_barrier() {
    asm volatile("s_waitcnt lgkmcnt(0)" ::: "memory");
    __builtin_amdgcn_s_barrier();
    asm volatile("" ::: "memory");
}
} // namespace

__launch_bounds__(768, 3)
__global__ void tvb_kernel(const float* __restrict__ region_pars,  // (128,1)
                           const float* __restrict__ Wt,           // (128,128,1)
                           const float* __restrict__ g,            // (1,)
                           const float* __restrict__ stimulus,     // (100,1)
                           const float* __restrict__ noise,        // (100,10,128,2)
                           const float* __restrict__ initial_cond, // (128,2)
                           const int*   __restrict__ lags,         // (128,128)
                           float* __restrict__ out)                // rv(1000,128,2) ++ bold(128)
{
    __shared__ float lds[HISTF + NREG];   // [0,HISTF): ring; then cbuf[128]
    char*  histc = (char*)lds;
    float* cbuf  = lds + HISTF;

    const int tid = (int)threadIdx.x;
    const int wid = tid >> 6;

    // ---- constants ----
    constexpr float ONE_PI = (float)(1.0 / 3.14159265358979323846);
    constexpr float PI_F   = (float)3.14159265358979323846;
    constexpr float RTS    = (float)(1.0 / 0.65);
    constexpr float RTF    = (float)(1.0 / 0.41);
    constexpr float RTO    = (float)(1.0 / 0.98);
    constexpr float K1     = (float)(4.3 * 40.3 * 0.4 * 0.04);
    constexpr float K2     = (float)(0.5 * 25.0 * 0.4 * 0.04);
    constexpr float L06    = -0.7369655941662062f;                  // log2(0.6)
    const float DWS = 0.01f * sqrtf(0.1f);

    // ---- init: r0 -> cbuf, then fill entire ring (all 257 slots) ----
    if (tid < NREG) cbuf[tid] = initial_cond[2 * tid];
    __syncthreads();
    for (int e = tid; e < HISTF; e += 768) lds[e] = cbuf[e & 127];
    __syncthreads();

    // ================= per-role persistent state =================
    float wreg[32]; int A[32];
    float aOld = 0.f, P0 = 0.f;
    int   nF = 0;
    float wF0=0,wF1=0,wF2=0,wF3=0,wF4=0,wF5=0,wF6=0,wF7=0;
    int   LJ0=0,LJ1=0,LJ2=0,LJ3=0,LJ4=0,LJ5=0,LJ6=0,LJ7=0;   // (lag<<20)|(j<<2)

    float xr=0.f, xV=0.f, eta=0.f, g0=0.f, c_cur=0.f;
    float2 nz = make_float2(0.f,0.f), nz_next = make_float2(0.f,0.f);
    float stim_i = 0.f, xb = 0.f;
    const int i2 = tid - 512;   // region for MPR waves
    const int i3 = tid - 640;   // region for BOLD waves
    float bs=1.f, bf=1.f, bv=1.f, bq=1.f;

    if (wid < 8) {
        const int h    = tid & 3;
        const int lane = tid & 63;
        const int rot  = (lane >> 2) + ((lane & 3) << 3);
        float sAll = 0.f, sOld = 0.f, p0i = 0.f;
#pragma unroll
        for (int k = 0; k < 32; ++k) {
            const int j  = (h << 5) | ((k + rot) & 31);
            const float ww = Wt[(tid >> 2) * NREG + j];
            const int lg = lags[(tid >> 2) * NREG + j];
            const int ph = (k < 16) ? 0 : 1;
            // first read (at s=ph) targets slot (2+ph-lag)&255; pre-decremented
            const int slot0 = (2 + ph - lg + 512) & 255;
            A[k] = (((slot0 << 9) | (j << 2)) + (0x20000 - 1024)) & 0x1FFFF;
            const float r0j = *(const float*)(histc + (j << 2));   // = r0_j
            if (lg <= 2) {
                wreg[k] = 0.f;
                const int lj = (lg << 20) | (j << 2);
                if      (nF == 0) { wF0 = ww; LJ0 = lj; }
                else if (nF == 1) { wF1 = ww; LJ1 = lj; }
                else if (nF == 2) { wF2 = ww; LJ2 = lj; }
                else if (nF == 3) { wF3 = ww; LJ3 = lj; }
                else if (nF == 4) { wF4 = ww; LJ4 = lj; }
                else if (nF == 5) { wF5 = ww; LJ5 = lj; }
                else if (nF == 6) { wF6 = ww; LJ6 = lj; }
                else              { wF7 = ww; LJ7 = lj; }
                ++nF;
                sAll = fmaf(ww, r0j, sAll);
            } else {
                wreg[k] = ww;
                sOld = fmaf(ww, r0j, sOld);
                sAll = fmaf(ww, r0j, sAll);
                if (k >= 16) p0i = fmaf(ww, r0j, p0i);   // odd group's vy for c(2)
            }
        }
        aOld = sOld;     // bulk part of c(1) (all r0)
        P0   = p0i;      // odd-group partial for c(2)
        float cful = dpp_add_xor1(sAll);
        cful = dpp_add_xor2(cful);
        if ((tid & 3) == 0) cbuf[tid >> 2] = cful;       // c(0)
    }
    __syncthreads();
    if (wid == 8 || wid == 9) {
        c_cur = cbuf[i2];
        eta   = region_pars[i2];
        g0    = g[0];
        xr    = initial_cond[2 * i2];
        xV    = initial_cond[2 * i2 + 1];
        nz    = *reinterpret_cast<const float2*>(&noise[(size_t)i2 * 2]);
    }
    __syncthreads();

    auto bstep = [&](float x) {
        const float pv1 = pow3125(bv);
        const float e1  = fexp2_raw(L06 * frcp_raw(bf));
        const float d1s = x - RTS * bs - RTF * (bf - 1.f);
        const float d1f = bs;
        const float d1v = RTO * (bf - pv1);
        const float d1q = RTO * (bf * (1.f - e1) * 2.5f - pv1 * bq * frcp_raw(bv));
        const float s2v = bs + 0.01f * d1s;
        const float f2v = bf + 0.01f * d1f;
        const float v2v = bv + 0.01f * d1v;
        const float q2v = bq + 0.01f * d1q;
        const float pv2 = pow3125(v2v);
        const float e2  = fexp2_raw(L06 * frcp_raw(f2v));
        const float d2s = x - RTS * s2v - RTF * (f2v - 1.f);
        const float d2f = s2v;
        const float d2v = RTO * (f2v - pv2);
        const float d2q = RTO * (f2v * (1.f - e2) * 2.5f - pv2 * q2v * frcp_raw(v2v));
        bs += 0.005f * (d1s + d2s);
        bf += 0.005f * (d1f + d2f);
        bv += 0.005f * (d1v + d2v);
        bq += 0.005f * (d1q + d2q);
    };

    auto stepBody = [&](auto PHC, int s) {
        constexpr int PH = decltype(PHC)::value;   // == s & 1
        // ---------- phase A ----------
        if (wid < 8) {
            float a = aOld;                         // bulk part of c(s+1)
            const int S1 = s + 1;
#define FRESH_ADD(c, WF, LJ) if (nF > c) { const int X = S1 - (LJ >> 20); \
            const int ad = ((X & 255) << 9) | (LJ & 0x3FC); \
            a = fmaf(WF, *(const float*)(histc + ad), a); }
            FRESH_ADD(0, wF0, LJ0) FRESH_ADD(1, wF1, LJ1) FRESH_ADD(2, wF2, LJ2) FRESH_ADD(3, wF3, LJ3)
            FRESH_ADD(4, wF4, LJ4) FRESH_ADD(5, wF5, LJ5) FRESH_ADD(6, wF6, LJ6) FRESH_ADD(7, wF7, LJ7)
#undef FRESH_ADD
            a = dpp_add_xor1(a);
            a = dpp_add_xor2(a);
            if ((tid & 3) == 0) cbuf[tid >> 2] = a; // c(s+1)
        } else if (wid < 10) {
            const int sn = (s < NSTEP - 1) ? s + 1 : NSTEP - 1;
            nz_next = *reinterpret_cast<const float2*>(&noise[(size_t)(sn * NREG + i2) * 2]);
            stim_i  = (i2 == 0) ? stimulus[s / 10] : 0.f;
        } else {
            xb = *(const float*)(histc + ((s & 255) << 9) + (i3 << 2));   // r(s)
        }
        wg_barrier();
        // ---------- phase B ----------
        if (wid < 8) {
            // readers this step: k in [K0, K0+16); fetch (r(s+2-lag), r(s+3-lag))
            constexpr int K0 = PH ? 16 : 0;
            float p0 = P0, p1 = 0.f;
#pragma unroll
            for (int k = K0; k < K0 + 16; ++k) {
                A[k] = (A[k] + 1024) & 0x1FFFF;
                const float* pp = (const float*)(histc + A[k]);
                const float vx = pp[0];     // r(s+2-lag)
                const float vy = pp[128];   // r(s+3-lag)  (merged ds_read2_b32)
                p0 = fmaf(wreg[k], vx, p0);
                p1 = fmaf(wreg[k], vy, p1);
            }
            aOld = p0;      // complete bulk part of c(s+2)
            P0   = p1;      // partial for c(s+3)
        } else if (wid < 10) {
            const float c_next = cbuf[i2];
            const float dw_r = DWS * nz.x;
            const float dw_V = DWS * nz.y;

            const float I1  = g0 * c_cur + stim_i;
            const float dr1 = ONE_PI + (2.0f * xr) * xV;
            const float p1  = PI_F * xr;
            const float dV1 = ((xV * xV + eta) + 15.0f * xr + I1) - p1 * p1;

            const float xir = fmaxf((xr + 0.1f * dr1) + dw_r, 0.f);
            const float xiV = (xV + 0.1f * dV1) + dw_V;

            const float I2  = g0 * c_next + stim_i;
            const float dr2 = ONE_PI + (2.0f * xir) * xiV;
            const float p2  = PI_F * xir;
            const float dV2 = ((xiV * xiV + eta) + 15.0f * xir + I2) - p2 * p2;

            const float nxr = fmaxf((xr + 0.05f * (dr1 + dr2)) + dw_r, 0.f);
            const float nxV = (xV + 0.05f * (dV1 + dV2)) + dw_V;

            const int sl = (s + 1) & 255;
            *(float*)(histc + (sl << 9) + (i2 << 2)) = nxr;
            if (sl == 0)                                        // keep dup row fresh
                *(float*)(histc + (256 << 9) + (i2 << 2)) = nxr;
            *reinterpret_cast<float2*>(&out[(size_t)(s * NREG + i2) * 2]) =
                make_float2(nxr, nxV);

            c_cur = c_next;
            xr = nxr;
            xV = nxV;
            nz = nz_next;
        } else {
            if (s > 0) bstep(xb);
        }
        wg_barrier();
    };

    for (int sp = 0; sp < NSTEP / 2; ++sp) {
        stepBody(std::integral_constant<int,0>{}, 2 * sp);
        stepBody(std::integral_constant<int,1>{}, 2 * sp + 1);
    }

    // ---- epilogue: last BOLD input r(1000), then bold output ----
    if (wid >= 10) {
        const float x = *(const float*)(histc + ((NSTEP & 255) << 9) + (i3 << 2));
        bstep(x);
        const float bold = 4.0f * (K1 * (1.f - bq) + K2 * (1.f - bq * frcp_raw(bv))
                                   + 0.5f * (1.f - bv));
        out[(size_t)NSTEP * NREG * 2 + i3] = bold;
    }
}

extern "C" void kernel_launch(void* const* d_in, const int* in_sizes, int n_in,
                              void* d_out, int out_size, void* d_ws, size_t ws_size,
                              hipStream_t stream) {
    const float* region_pars  = (const float*)d_in[0];
    const float* Wt           = (const float*)d_in[1];
    const float* g            = (const float*)d_in[2];
    const float* stimulus     = (const float*)d_in[3];
    const float* noise        = (const float*)d_in[4];
    const float* initial_cond = (const float*)d_in[5];
    const int*   lags         = (const int*)d_in[6];
    // d_in[7] = ix_lag_from: always tile(arange(N)) -> implicit in our layout

    tvb_kernel<<<dim3(1), dim3(768), 0, stream>>>(
        region_pars, Wt, g, stimulus, noise, initial_cond, lags, (float*)d_out);
}

// Round 6
// 648.781 us; speedup vs baseline: 1.9314x; 1.7700x over previous
//
#include <hip/hip_runtime.h>
#include <math.h>
#include <type_traits>

// TVB MPR simulation + BOLD, v6: merged-role single-barrier step with
// guaranteed ds_read_b64 time-pairing on a 65-unit dual-copy ring.
//
// 640 threads = 10 waves:
//   tid 0..511  : gather+MPR. 4 threads/region, 32 term-slots each.
//                 Slot k reads on steps s with (s&1)==(k&1): ONE float2
//                 (ds_read_b64) = (r(s+1-lag), r(s+2-lag)) -> contributions
//                 to c(s+1) (consumed now) and c(s+2) (carried). lag==1
//                 terms are "fresh": 4 branchless padded b32 reads of r(s).
//                 After dpp-quad reduce, all 4 lanes compute MPR redundantly;
//                 lane (tid&3)==0 writes the ring + rv output.
//   tid 512..639: BOLD Heun chain (reads r(s) from ring, concurrent).
//
// Ring: 65 units x 2048 B (133120 B). Unit P: [0,1024) copyA = times
// (2P, 2P+1) mod 130; [1024,2048) copyB = times (2P+1, 2P+2); each row is
// float2 per region j at j*8. 65 units (not 64) => the step-s write of
// r(s+1) clobbers times (s-129,s-128), outside the read window [s-127, s],
// so reads and writes share one phase race-free. Wrap via unsigned-min.
//
// ONE raw barrier per step (lgkmcnt only -- no vmcnt drain, so noise loads
// and rv stores stay in flight across steps).

namespace {
constexpr int NREG  = 128;
constexpr int NSTEP = 1000;
constexpr int UNITS = 65;
constexpr unsigned RING_BYTES = UNITS * 2048u;      // 133120
constexpr int RING_FLOATS = (int)(RING_BYTES / 4);  // 33280

__device__ __forceinline__ float fsqrt_raw(float x){ float r; asm("v_sqrt_f32 %0, %1" : "=v"(r) : "v"(x)); return r; }
__device__ __forceinline__ float frcp_raw (float x){ float r; asm("v_rcp_f32 %0, %1" : "=v"(r) : "v"(x)); return r; }
__device__ __forceinline__ float fexp2_raw(float x){ float r; asm("v_exp_f32 %0, %1" : "=v"(r) : "v"(x)); return r; }

__device__ __forceinline__ float pow3125(float v) {
    float s1 = fsqrt_raw(v);
    float s2 = fsqrt_raw(s1);
    float s3 = fsqrt_raw(s2);
    return v * v * v * s3;
}

__device__ __forceinline__ float dpp_add_xor1(float x){
    int y = __builtin_amdgcn_mov_dpp(__float_as_int(x), 0xB1, 0xF, 0xF, true); // [1,0,3,2]
    return x + __int_as_float(y);
}
__device__ __forceinline__ float dpp_add_xor2(float x){
    int y = __builtin_amdgcn_mov_dpp(__float_as_int(x), 0x4E, 0xF, 0xF, true); // [2,3,0,1]
    return x + __int_as_float(y);
}

// raw workgroup barrier: LDS drained, global ops keep flying (no vmcnt(0))
__device__ __forceinline__ void wg_barrier() {
    asm volatile("s_waitcnt lgkmcnt(0)" ::: "memory");
    __builtin_amdgcn_s_barrier();
    asm volatile("" ::: "memory");
}
} // namespace

__launch_bounds__(640, 2)
__global__ void tvb_kernel(const float* __restrict__ region_pars,  // (128,1)
                           const float* __restrict__ Wt,           // (128,128,1)
                           const float* __restrict__ g,            // (1,)
                           const float* __restrict__ stimulus,     // (100,1)
                           const float* __restrict__ noise,        // (100,10,128,2)
                           const float* __restrict__ initial_cond, // (128,2)
                           const int*   __restrict__ lags,         // (128,128)
                           float* __restrict__ out)                // rv(1000,128,2) ++ bold(128)
{
    __shared__ float lds[RING_FLOATS];   // 130 KB pair ring
    char* histc = (char*)lds;

    const int tid = (int)threadIdx.x;
    const bool isG = tid < 512;
    const int i  = tid >> 2;      // gather region
    const int h  = tid & 3;
    const int i3 = tid - 512;     // BOLD region

    // ---- constants ----
    constexpr float ONE_PI = (float)(1.0 / 3.14159265358979323846);
    constexpr float PI_F   = (float)3.14159265358979323846;
    constexpr float RTS    = (float)(1.0 / 0.65);
    constexpr float RTF    = (float)(1.0 / 0.41);
    constexpr float RTO    = (float)(1.0 / 0.98);
    constexpr float K1     = (float)(4.3 * 40.3 * 0.4 * 0.04);
    constexpr float K2     = (float)(0.5 * 25.0 * 0.4 * 0.04);
    constexpr float L06    = -0.7369655941662062f;                  // log2(0.6)
    const float DWS = 0.01f * sqrtf(0.1f);

    // ---- init: whole ring = r0 (float index f: region j = (f>>1)&127) ----
    for (int e = tid; e < RING_FLOATS; e += 640)
        lds[e] = initial_cond[2 * ((e >> 1) & 127)];
    __syncthreads();

    // ================= per-role persistent state =================
    float w[32]; unsigned A[32];
    float wf0=0,wf1=0,wf2=0,wf3=0;
    int   jf0=0,jf1=0,jf2=0,jf3=0;          // j*8 byte offsets (pad 0)
    float carry = 0.f, c_cur = 0.f;
    float xr=0.f, xV=0.f, eta=0.f, g0=0.f;
    float2 nz = make_float2(0.f,0.f);
    float stim_cur = 0.f;
    float bs=1.f, bf=1.f, bv=1.f, bq=1.f;

    if (isG) {
        const int lane = tid & 63;
        const int rot  = (lane >> 2) + ((lane & 3) << 3);
        float sAll = 0.f, sOdd = 0.f;
        int nF = 0;
#pragma unroll
        for (int k = 0; k < 32; ++k) {
            const int j  = (h << 5) | ((k + rot) & 31);
            const float ww = Wt[i * NREG + j];
            int lg = lags[i * NREG + j];
            const float r0j = *(const float*)(histc + (j << 3));   // time0 = r0_j
            sAll = fmaf(ww, r0j, sAll);
            float wp = ww;
            if (lg == 1) {                    // fresh term
                wp = 0.f;
                if      (nF == 0) { wf0 = ww; jf0 = j << 3; }
                else if (nF == 1) { wf1 = ww; jf1 = j << 3; }
                else if (nF == 2) { wf2 = ww; jf2 = j << 3; }
                else              { wf3 = ww; jf3 = j << 3; }
                ++nF;
                lg = 2;                       // safe addr for the dead slot
            }
            w[k] = wp;
            if (k & 1) sOdd = fmaf(wp, r0j, sOdd);
            // first read (at s = k&1) targets pair starting T0 = (k&1)+1-lg
            const int Tb   = (k & 1) + 1 - lg + 260;       // >= 133, parity kept
            const int unit = (Tb >> 1) % UNITS;
            int A0 = unit * 2048 + (Tb & 1) * 1024 + (j << 3);
            A0 -= 2048;                                     // pre-decrement
            if (A0 < 0) A0 += (int)RING_BYTES;
            A[k] = (unsigned)A0;
        }
        carry = sOdd;                        // odd slots' part of c(1) (all r0)
        sAll = dpp_add_xor1(sAll);
        sAll = dpp_add_xor2(sAll);
        c_cur = sAll;                        // c(0)
        eta = region_pars[i];
        g0  = g[0];
        xr  = initial_cond[2 * i];
        xV  = initial_cond[2 * i + 1];
        nz  = *reinterpret_cast<const float2*>(&noise[(size_t)i * 2]);
        stim_cur = stimulus[0];
    }
    __syncthreads();   // protect prologue ring reads from step-0 writes

    auto bstep = [&](float x) {
        const float pv1 = pow3125(bv);
        const float e1  = fexp2_raw(L06 * frcp_raw(bf));
        const float d1s = x - RTS * bs - RTF * (bf - 1.f);
        const float d1f = bs;
        const float d1v = RTO * (bf - pv1);
        const float d1q = RTO * (bf * (1.f - e1) * 2.5f - pv1 * bq * frcp_raw(bv));
        const float s2v = bs + 0.01f * d1s;
        const float f2v = bf + 0.01f * d1f;
        const float v2v = bv + 0.01f * d1v;
        const float q2v = bq + 0.01f * d1q;
        const float pv2 = pow3125(v2v);
        const float e2  = fexp2_raw(L06 * frcp_raw(f2v));
        const float d2s = x - RTS * s2v - RTF * (f2v - 1.f);
        const float d2f = s2v;
        const float d2v = RTO * (f2v - pv2);
        const float d2q = RTO * (f2v * (1.f - e2) * 2.5f - pv2 * q2v * frcp_raw(v2v));
        bs += 0.005f * (d1s + d2s);
        bf += 0.005f * (d1f + d2f);
        bv += 0.005f * (d1v + d2v);
        bq += 0.005f * (d1q + d2q);
    };

    auto stepBody = [&](auto PHC, int s) {
        constexpr int PH = decltype(PHC)::value;         // == s & 1
        if (isG) {
            // prefetch next step's inputs (latency hides across the barrier)
            const int sn = (s < NSTEP - 1) ? s + 1 : NSTEP - 1;
            const float2 nz_next =
                *reinterpret_cast<const float2*>(&noise[(size_t)(sn * NREG + i) * 2]);
            const float stim_next = stimulus[sn / 10];

            // ---- paired bulk gather: due slots (k&1)==PH ----
            float anow = carry, anext = 0.f;
#pragma unroll
            for (int k = 0; k < 32; ++k) {
                if ((k & 1) == PH) {
                    unsigned a2 = A[k] + 2048u;
                    a2 = min(a2, a2 - RING_BYTES);          // mod-65 wrap
                    A[k] = a2;
                    const float2 v = *reinterpret_cast<const float2*>(histc + a2);
                    anow  = fmaf(w[k], v.x, anow);          // -> c(s+1)
                    anext = fmaf(w[k], v.y, anext);         // -> c(s+2)
                }
            }
            // ---- fresh (lag==1) terms read r(s) ----
            const int rowS = ((s >> 1) % UNITS) * 2048 + ((s & 1) << 2);
            anow = fmaf(wf0, *(const float*)(histc + rowS + jf0), anow);
            anow = fmaf(wf1, *(const float*)(histc + rowS + jf1), anow);
            anow = fmaf(wf2, *(const float*)(histc + rowS + jf2), anow);
            anow = fmaf(wf3, *(const float*)(histc + rowS + jf3), anow);
            anow = dpp_add_xor1(anow);
            anow = dpp_add_xor2(anow);
            const float c_next = anow;                      // c(s+1)

            // ---- MPR Heun (redundant in all 4 lanes of the quad) ----
            const float stim_i = (i == 0) ? stim_cur : 0.f;
            const float dw_r = DWS * nz.x;
            const float dw_V = DWS * nz.y;

            const float I1  = g0 * c_cur + stim_i;
            const float dr1 = ONE_PI + (2.0f * xr) * xV;
            const float p1  = PI_F * xr;
            const float dV1 = ((xV * xV + eta) + 15.0f * xr + I1) - p1 * p1;

            const float xir = fmaxf((xr + 0.1f * dr1) + dw_r, 0.f);
            const float xiV = (xV + 0.1f * dV1) + dw_V;

            const float I2  = g0 * c_next + stim_i;
            const float dr2 = ONE_PI + (2.0f * xir) * xiV;
            const float p2  = PI_F * xir;
            const float dV2 = ((xiV * xiV + eta) + 15.0f * xir + I2) - p2 * p2;

            const float nxr = fmaxf((xr + 0.05f * (dr1 + dr2)) + dw_r, 0.f);
            const float nxV = (xV + 0.05f * (dV1 + dV2)) + dw_V;

            if ((tid & 3) == 0) {
                const int X = s + 1;
                // copyA: unit (X>>1)%65, dword X&1
                *(float*)(histc + ((X >> 1) % UNITS) * 2048
                                + ((X & 1) << 2) + (i << 3)) = nxr;
                // copyB: unit ((X-1)>>1)%65, +1024, dword (X&1)^1
                *(float*)(histc + (((X - 1) >> 1) % UNITS) * 2048 + 1024
                                + (((X & 1) ^ 1) << 2) + (i << 3)) = nxr;
                *reinterpret_cast<float2*>(&out[(size_t)(s * NREG + i) * 2]) =
                    make_float2(nxr, nxV);
            }

            carry = anext;
            c_cur = c_next;
            xr = nxr; xV = nxV;
            nz = nz_next;
            stim_cur = stim_next;
        } else {
            // ---- BOLD: consume r(s) (written at step s-1) ----
            if (s > 0) {
                const int rowS = ((s >> 1) % UNITS) * 2048 + ((s & 1) << 2);
                const float xb = *(const float*)(histc + rowS + (i3 << 3));
                bstep(xb);
            }
        }
        wg_barrier();
    };

    for (int sp = 0; sp < NSTEP / 2; ++sp) {
        stepBody(std::integral_constant<int,0>{}, 2 * sp);
        stepBody(std::integral_constant<int,1>{}, 2 * sp + 1);
    }

    // ---- epilogue: last BOLD input r(1000), then bold output ----
    if (!isG) {
        const int rowS = ((NSTEP >> 1) % UNITS) * 2048 + ((NSTEP & 1) << 2);
        const float x = *(const float*)(histc + rowS + (i3 << 3));
        bstep(x);
        const float bold = 4.0f * (K1 * (1.f - bq) + K2 * (1.f - bq * frcp_raw(bv))
                                   + 0.5f * (1.f - bv));
        out[(size_t)NSTEP * NREG * 2 + i3] = bold;
    }
}

extern "C" void kernel_launch(void* const* d_in, const int* in_sizes, int n_in,
                              void* d_out, int out_size, void* d_ws, size_t ws_size,
                              hipStream_t stream) {
    const float* region_pars  = (const float*)d_in[0];
    const float* Wt           = (const float*)d_in[1];
    const float* g            = (const float*)d_in[2];
    const float* stimulus     = (const float*)d_in[3];
    const float* noise        = (const float*)d_in[4];
    const float* initial_cond = (const float*)d_in[5];
    const int*   lags         = (const int*)d_in[6];
    // d_in[7] = ix_lag_from: always tile(arange(N)) -> implicit in our layout

    tvb_kernel<<<dim3(1), dim3(640), 0, stream>>>(
        region_pars, Wt, g, stimulus, noise, initial_cond, lags, (float*)d_out);
}